// Round 2
// baseline (130.068 us; speedup 1.0000x reference)
//
#include <hip/hip_runtime.h>

typedef float2 c32;

__device__ __forceinline__ c32 cmul(c32 a, c32 b) {
    return make_float2(a.x * b.x - a.y * b.y, a.x * b.y + a.y * b.x);
}
__device__ __forceinline__ c32 cmad(c32 a, c32 b, c32 acc) {
    acc.x = fmaf(a.x, b.x, fmaf(-a.y, b.y, acc.x));
    acc.y = fmaf(a.x, b.y, fmaf(a.y, b.x, acc.y));
    return acc;
}

// ---------------- gate-matrix precompute: 20 threads, one column each ------

__device__ __forceinline__ void mk_u3(float th, float ph, float la, c32 U[2][2]) {
    float ct = cosf(0.5f * th), st = sinf(0.5f * th);
    U[0][0] = make_float2(ct, 0.f);
    U[0][1] = make_float2(-cosf(la) * st, -sinf(la) * st);
    U[1][0] = make_float2(cosf(ph) * st, sinf(ph) * st);
    U[1][1] = make_float2(cosf(ph + la) * ct, sinf(ph + la) * ct);
}

// m (a column of M) <- kron(A,B) * m
__device__ __forceinline__ void lmul_kron(const c32 A[2][2], const c32 B[2][2], c32 m[4]) {
    c32 t[4];
#pragma unroll
    for (int r = 0; r < 4; ++r) {
        c32 acc = make_float2(0.f, 0.f);
#pragma unroll
        for (int k = 0; k < 4; ++k)
            acc = cmad(cmul(A[r >> 1][k >> 1], B[r & 1][k & 1]), m[k], acc);
        t[r] = acc;
    }
#pragma unroll
    for (int r = 0; r < 4; ++r) m[r] = t[r];
}

__global__ void build_gates_kernel(const float* __restrict__ w, c32* __restrict__ mats) {
    const int t = threadIdx.x;
    if (t >= 20) return;
    const int g = t >> 2, c = t & 3;
    const float* p = w + g * 15;
    const int c0 = c >> 1, c1 = c & 1;
    c32 A[2][2], B[2][2], m[4], tmp;

    // col c of kron(u3(p0,p1,p2), u3(p3,p4,p5))
    mk_u3(p[0], p[1], p[2], A);
    mk_u3(p[3], p[4], p[5], B);
#pragma unroll
    for (int r = 0; r < 4; ++r) m[r] = cmul(A[r >> 1][c0], B[r & 1][c1]);
    // CNOT(w0->w1): swap rows 2,3
    tmp = m[2]; m[2] = m[3]; m[3] = tmp;
    // ry(p6) (x) rz(p7)
    {
        float cc = cosf(0.5f * p[6]), s = sinf(0.5f * p[6]);
        A[0][0] = make_float2(cc, 0.f); A[0][1] = make_float2(-s, 0.f);
        A[1][0] = make_float2(s, 0.f);  A[1][1] = make_float2(cc, 0.f);
        float cz = cosf(0.5f * p[7]), sz = sinf(0.5f * p[7]);
        B[0][0] = make_float2(cz, -sz); B[0][1] = make_float2(0.f, 0.f);
        B[1][0] = make_float2(0.f, 0.f); B[1][1] = make_float2(cz, sz);
        lmul_kron(A, B, m);
    }
    // CNOT(w1->w0): swap rows 1,3
    tmp = m[1]; m[1] = m[3]; m[3] = tmp;
    // ry(p8) (x) I
    {
        float cc = cosf(0.5f * p[8]), s = sinf(0.5f * p[8]);
        A[0][0] = make_float2(cc, 0.f); A[0][1] = make_float2(-s, 0.f);
        A[1][0] = make_float2(s, 0.f);  A[1][1] = make_float2(cc, 0.f);
        B[0][0] = make_float2(1.f, 0.f); B[0][1] = make_float2(0.f, 0.f);
        B[1][0] = make_float2(0.f, 0.f); B[1][1] = make_float2(1.f, 0.f);
        lmul_kron(A, B, m);
    }
    // CNOT(w0->w1)
    tmp = m[2]; m[2] = m[3]; m[3] = tmp;
    // kron(u3(p9..11), u3(p12..14))
    mk_u3(p[9], p[10], p[11], A);
    mk_u3(p[12], p[13], p[14], B);
    lmul_kron(A, B, m);
#pragma unroll
    for (int r = 0; r < 4; ++r) mats[g * 16 + r * 4 + c] = m[r];
}

// ---------------- register-resident simulator: 1 wave per state -----------

// swap storage roles of reg-bit SLOT and lane-bit L
template<int SLOT, int L>
__device__ __forceinline__ void swapop(c32 s[4], int lane) {
    const bool hi = (lane >> L) & 1;
#pragma unroll
    for (int f = 0; f < 2; ++f) {
        const int A = SLOT ? (2 + f) : (2 * f + 1);
        const int B = SLOT ? (0 + f) : (2 * f + 0);
        c32 send = hi ? s[B] : s[A];
        c32 recv;
        recv.x = __shfl_xor(send.x, 1 << L, 64);
        recv.y = __shfl_xor(send.y, 1 << L, 64);
        if (hi) s[B] = recv; else s[A] = recv;
    }
}

// apply 4x4 gate held in m[] to s[]; O=1 means reg bits are (p1,p0) order
template<int O>
__device__ __forceinline__ void gateop(const c32 m[16], c32 s[4]) {
    constexpr int P0[4] = {0, 1, 2, 3};
    constexpr int P1[4] = {0, 2, 1, 3};
    c32 t[4];
#pragma unroll
    for (int r = 0; r < 4; ++r) {
        const int rr = O ? P1[r] : P0[r];
        c32 acc = cmul(m[rr * 4 + (O ? P1[0] : P0[0])], s[0]);
        acc = cmad(m[rr * 4 + (O ? P1[1] : P0[1])], s[1], acc);
        acc = cmad(m[rr * 4 + (O ? P1[2] : P0[2])], s[2], acc);
        acc = cmad(m[rr * 4 + (O ? P1[3] : P0[3])], s[3], acc);
        t[r] = acc;
    }
#pragma unroll
    for (int r = 0; r < 4; ++r) s[r] = t[r];
}

__global__ __launch_bounds__(256) void sim_kernel(const float* __restrict__ x,
                                                  const c32* __restrict__ gmats,
                                                  float* __restrict__ out) {
    __shared__ c32 GM[80];
    const int tid = threadIdx.x;
    const int wv = tid >> 6, lane = tid & 63;
    if (tid < 80) GM[tid] = gmats[tid];
    __syncthreads();

    const int b = blockIdx.x * 4 + wv;
    const float4 xv = *reinterpret_cast<const float4*>(x + (size_t)b * 256 + lane * 4);
    float ss = xv.x * xv.x + xv.y * xv.y + xv.z * xv.z + xv.w * xv.w;
#pragma unroll
    for (int o = 32; o; o >>= 1) ss += __shfl_xor(ss, o, 64);
    const float inv = 1.0f / sqrtf(ss);

    // state: reg index r holds phys bits (rb1,rb0); initially (1,0), lane bits = phys 7..2
    c32 s[4];
    s[0] = make_float2(xv.x * inv, 0.f);
    s[1] = make_float2(xv.y * inv, 0.f);
    s[2] = make_float2(xv.z * inv, 0.f);
    s[3] = make_float2(xv.w * inv, 0.f);

    c32 m[16];
#define LOADM(LI) _Pragma("unroll") for (int k = 0; k < 16; ++k) m[k] = GM[(LI) * 16 + k];
#define SW(SLOT, L) swapop<SLOT, L>(s, lane)
#define GT(O) gateop<O>(m, s)

    // ---- layer 1, pass 1 (mat 0): (1,0),(7,6),(0,7),(5,4),(6,5),(3,2),(4,3),(2,1)
    LOADM(0);
    GT(0);                       // (1,0)
    SW(1,5); SW(0,4); GT(0);     // (7,6)
    SW(0,4);          GT(1);     // (0,7)
    SW(1,3); SW(0,2); GT(0);     // (5,4)
    SW(0,4);          GT(1);     // (6,5)
    SW(1,1); SW(0,0); GT(0);     // (3,2)
    SW(0,4);          GT(1);     // (4,3)
    SW(1,4); SW(0,5); GT(0);     // (2,1)
    // ---- layer 1, pass 2 (mat 1)
    LOADM(1);
    SW(1,2);          GT(1);     // (1,0)
    SW(1,3); SW(0,0); GT(0);     // (7,6)
    SW(0,3);          GT(1);     // (0,7)
    SW(1,1); SW(0,5); GT(0);     // (5,4)
    SW(0,3);          GT(1);     // (6,5)
    SW(1,4); SW(0,2); GT(0);     // (3,2)
    SW(0,3);          GT(1);     // (4,3)
    SW(1,3); SW(0,0); GT(0);     // (2,1)
    // ---- layer 2, pass 1 (mat 2): (1,7),(5,3),(7,5),(3,1)
    LOADM(2);
    SW(1,1);          GT(1);     // (1,7)
    SW(1,4); SW(0,3); GT(0);     // (5,3)
    SW(0,4);          GT(1);     // (7,5)
    SW(1,4); SW(0,3); GT(0);     // (3,1)
    // ---- layer 2, pass 2 (mat 3): (1,7),(5,3),(3,1),(7,5)
    LOADM(3);
    SW(1,3);          GT(1);     // (1,7)
    SW(1,4); SW(0,3); GT(0);     // (5,3)
    SW(1,3);          GT(1);     // (3,1)
    SW(1,4); SW(0,3); GT(0);     // (7,5)
    // ---- layer 3 (mat 4): (5,1)
    LOADM(4);
    SW(1,4);          GT(1);     // (5,1)  -> final: rb1 = phys1 (qubit6), rb0 = phys5 (qubit2)

    // ---- expectations: both measured bits are register-resident
    // r = 2*b(q6) + b(q2)
    float re01 = s[0].x * s[1].x + s[0].y * s[1].y;  // Re(conj s0 * s1)
    float im01 = s[0].x * s[1].y - s[0].y * s[1].x;
    float re23 = s[2].x * s[3].x + s[2].y * s[3].y;
    float im23 = s[2].x * s[3].y - s[2].y * s[3].x;
    float re02 = s[0].x * s[2].x + s[0].y * s[2].y;
    float im02 = s[0].x * s[2].y - s[0].y * s[2].x;
    float re13 = s[1].x * s[3].x + s[1].y * s[3].y;
    float im13 = s[1].x * s[3].y - s[1].y * s[3].x;
    float re03 = s[0].x * s[3].x + s[0].y * s[3].y;
    float re12 = s[1].x * s[2].x + s[1].y * s[2].y;
    float n0 = s[0].x * s[0].x + s[0].y * s[0].y;
    float n1 = s[1].x * s[1].x + s[1].y * s[1].y;
    float n2 = s[2].x * s[2].x + s[2].y * s[2].y;
    float n3 = s[3].x * s[3].x + s[3].y * s[3].y;

    float e[9];
    e[0] = 2.f * (re01 + re23);          // X on qubit2
    e[1] = 2.f * (im01 + im23);          // Y on qubit2
    e[2] = n0 - n1 + n2 - n3;            // Z on qubit2
    e[3] = 2.f * (re02 + re13);          // X on qubit6
    e[4] = 2.f * (im02 + im13);          // Y on qubit6
    e[5] = n0 + n1 - n2 - n3;            // Z on qubit6
    e[6] = 2.f * (re03 + re12);          // X2 X6
    e[7] = 2.f * (re12 - re03);          // Y2 Y6
    e[8] = n0 - n1 - n2 + n3;            // Z2 Z6

#pragma unroll
    for (int mm = 0; mm < 9; ++mm) {
        float v = e[mm];
#pragma unroll
        for (int o = 32; o; o >>= 1) v += __shfl_xor(v, o, 64);
        e[mm] = v;
    }
    if (lane == 0) {
#pragma unroll
        for (int mm = 0; mm < 9; ++mm) out[b * 9 + mm] = e[mm];
    }
#undef LOADM
#undef SW
#undef GT
}

extern "C" void kernel_launch(void* const* d_in, const int* in_sizes, int n_in,
                              void* d_out, int out_size, void* d_ws, size_t ws_size,
                              hipStream_t stream) {
    const float* x = (const float*)d_in[0];
    const float* w = (const float*)d_in[1];
    float* out = (float*)d_out;
    c32* mats = (c32*)d_ws;

    hipLaunchKernelGGL(build_gates_kernel, dim3(1), dim3(64), 0, stream, w, mats);

    const int batch = in_sizes[0] / 256;   // 8192
    const int nblocks = batch / 4;         // 4 waves (states) per block
    hipLaunchKernelGGL(sim_kernel, dim3(nblocks), dim3(256), 0, stream, x, mats, out);
}

// Round 3
// 60.448 us; speedup vs baseline: 2.1517x; 2.1517x over previous
//
#include <hip/hip_runtime.h>

typedef float2 c32;

__device__ __forceinline__ c32 cmul(c32 a, c32 b) {
    return make_float2(a.x * b.x - a.y * b.y, a.x * b.y + a.y * b.x);
}
__device__ __forceinline__ c32 cmad(c32 a, c32 b, c32 acc) {
    acc.x = fmaf(a.x, b.x, fmaf(-a.y, b.y, acc.x));
    acc.y = fmaf(a.x, b.y, fmaf(a.y, b.x, acc.y));
    return acc;
}

// ---------------- gate-matrix precompute: 20 threads, one column each ------

__device__ __forceinline__ void mk_u3(float th, float ph, float la, c32 U[2][2]) {
    float ct = cosf(0.5f * th), st = sinf(0.5f * th);
    U[0][0] = make_float2(ct, 0.f);
    U[0][1] = make_float2(-cosf(la) * st, -sinf(la) * st);
    U[1][0] = make_float2(cosf(ph) * st, sinf(ph) * st);
    U[1][1] = make_float2(cosf(ph + la) * ct, sinf(ph + la) * ct);
}

// m (a column of M) <- kron(A,B) * m
__device__ __forceinline__ void lmul_kron(const c32 A[2][2], const c32 B[2][2], c32 m[4]) {
    c32 t[4];
#pragma unroll
    for (int r = 0; r < 4; ++r) {
        c32 acc = make_float2(0.f, 0.f);
#pragma unroll
        for (int k = 0; k < 4; ++k)
            acc = cmad(cmul(A[r >> 1][k >> 1], B[r & 1][k & 1]), m[k], acc);
        t[r] = acc;
    }
#pragma unroll
    for (int r = 0; r < 4; ++r) m[r] = t[r];
}

__global__ void build_gates_kernel(const float* __restrict__ w, c32* __restrict__ mats) {
    const int t = threadIdx.x;
    if (t >= 20) return;
    const int g = t >> 2, c = t & 3;
    const float* p = w + g * 15;
    const int c0 = c >> 1, c1 = c & 1;
    c32 A[2][2], B[2][2], m[4], tmp;

    // col c of kron(u3(p0,p1,p2), u3(p3,p4,p5))
    mk_u3(p[0], p[1], p[2], A);
    mk_u3(p[3], p[4], p[5], B);
#pragma unroll
    for (int r = 0; r < 4; ++r) m[r] = cmul(A[r >> 1][c0], B[r & 1][c1]);
    // CNOT(w0->w1): swap rows 2,3
    tmp = m[2]; m[2] = m[3]; m[3] = tmp;
    // ry(p6) (x) rz(p7)
    {
        float cc = cosf(0.5f * p[6]), s = sinf(0.5f * p[6]);
        A[0][0] = make_float2(cc, 0.f); A[0][1] = make_float2(-s, 0.f);
        A[1][0] = make_float2(s, 0.f);  A[1][1] = make_float2(cc, 0.f);
        float cz = cosf(0.5f * p[7]), sz = sinf(0.5f * p[7]);
        B[0][0] = make_float2(cz, -sz); B[0][1] = make_float2(0.f, 0.f);
        B[1][0] = make_float2(0.f, 0.f); B[1][1] = make_float2(cz, sz);
        lmul_kron(A, B, m);
    }
    // CNOT(w1->w0): swap rows 1,3
    tmp = m[1]; m[1] = m[3]; m[3] = tmp;
    // ry(p8) (x) I
    {
        float cc = cosf(0.5f * p[8]), s = sinf(0.5f * p[8]);
        A[0][0] = make_float2(cc, 0.f); A[0][1] = make_float2(-s, 0.f);
        A[1][0] = make_float2(s, 0.f);  A[1][1] = make_float2(cc, 0.f);
        B[0][0] = make_float2(1.f, 0.f); B[0][1] = make_float2(0.f, 0.f);
        B[1][0] = make_float2(0.f, 0.f); B[1][1] = make_float2(1.f, 0.f);
        lmul_kron(A, B, m);
    }
    // CNOT(w0->w1)
    tmp = m[2]; m[2] = m[3]; m[3] = tmp;
    // kron(u3(p9..11), u3(p12..14))
    mk_u3(p[9], p[10], p[11], A);
    mk_u3(p[12], p[13], p[14], B);
    lmul_kron(A, B, m);
#pragma unroll
    for (int r = 0; r < 4; ++r) mats[g * 16 + r * 4 + c] = m[r];
}

// ---------------- main simulator: 1 wave per batch state, barrier-free ----

__device__ __forceinline__ int swz(int i) { return i ^ (i >> 4); }

__global__ __launch_bounds__(256) void sim_kernel(const float* __restrict__ x,
                                                  const c32* __restrict__ gmats,
                                                  float* __restrict__ out) {
    __shared__ c32 S[4][256];
    __shared__ c32 GM[5][16];
    const int tid = threadIdx.x;
    const int wv = tid >> 6, lane = tid & 63;
    if (tid < 80) (&GM[0][0])[tid] = gmats[tid];
    __syncthreads();   // the ONLY barrier: GM is shared across waves

    const int b = blockIdx.x * 4 + wv;
    const float* xr = x + (size_t)b * 256;

    // load row, compute norm, write normalized real state into swizzled LDS
    float v0 = xr[lane], v1 = xr[lane + 64], v2 = xr[lane + 128], v3 = xr[lane + 192];
    float ss = v0 * v0 + v1 * v1 + v2 * v2 + v3 * v3;
#pragma unroll
    for (int o = 32; o; o >>= 1) ss += __shfl_xor(ss, o, 64);
    float inv = 1.0f / sqrtf(ss);
    S[wv][swz(lane)]       = make_float2(v0 * inv, 0.f);
    S[wv][swz(lane + 64)]  = make_float2(v1 * inv, 0.f);
    S[wv][swz(lane + 128)] = make_float2(v2 * inv, 0.f);
    S[wv][swz(lane + 192)] = make_float2(v3 * inv, 0.f);
    // no barrier: S[wv] is private to this wave; in-wave LDS ordering is
    // enforced by compiler-inserted lgkmcnt waits.

    // gate list: (layer param-set, bit positions p = 7 - wire)
    constexpr int g_li[25] = {0,0,0,0,0,0,0,0, 1,1,1,1,1,1,1,1, 2,2,2,2, 3,3,3,3, 4};
    constexpr int g_p0[25] = {7,5,3,1,6,4,2,0, 7,5,3,1,6,4,2,0, 5,1,7,3, 5,1,7,3, 5};
    constexpr int g_p1[25] = {6,4,2,0,5,3,1,7, 6,4,2,0,5,3,1,7, 3,7,5,1, 3,7,5,1, 1};

#pragma unroll
    for (int g = 0; g < 25; ++g) {
        const int p0 = g_p0[g], p1 = g_p1[g];
        const int lo = (p0 < p1) ? p0 : p1;
        const int hi = (p0 < p1) ? p1 : p0;
        // spread 6-bit lane index over the 6 free bit positions
        int t1   = ((lane & ~((1 << lo) - 1)) << 1) | (lane & ((1 << lo) - 1));
        int base = ((t1 & ~((1 << hi) - 1)) << 1) | (t1 & ((1 << hi) - 1));
        const int i00 = base;
        const int i01 = base | (1 << p1);
        const int i10 = base | (1 << p0);
        const int i11 = i10 | (1 << p1);
        c32 a0 = S[wv][swz(i00)];
        c32 a1 = S[wv][swz(i01)];
        c32 a2 = S[wv][swz(i10)];
        c32 a3 = S[wv][swz(i11)];
        const c32* M = GM[g_li[g]];
        c32 r0 = cmul(M[0],  a0); r0 = cmad(M[1],  a1, r0); r0 = cmad(M[2],  a2, r0); r0 = cmad(M[3],  a3, r0);
        c32 r1 = cmul(M[4],  a0); r1 = cmad(M[5],  a1, r1); r1 = cmad(M[6],  a2, r1); r1 = cmad(M[7],  a3, r1);
        c32 r2 = cmul(M[8],  a0); r2 = cmad(M[9],  a1, r2); r2 = cmad(M[10], a2, r2); r2 = cmad(M[11], a3, r2);
        c32 r3 = cmul(M[12], a0); r3 = cmad(M[13], a1, r3); r3 = cmad(M[14], a2, r3); r3 = cmad(M[15], a3, r3);
        S[wv][swz(i00)] = r0;
        S[wv][swz(i01)] = r1;
        S[wv][swz(i10)] = r2;
        S[wv][swz(i11)] = r3;
        // no barrier
    }

    // expectations: qubit 2 -> bit 5, qubit 6 -> bit 1
    float e0 = 0, e1 = 0, e2 = 0, e3 = 0, e4 = 0, e5 = 0, e6 = 0, e7 = 0, e8 = 0;
#pragma unroll
    for (int k = 0; k < 4; ++k) {
        const int i = lane + 64 * k;
        c32 a = S[wv][swz(i)];
        float pr = a.x * a.x + a.y * a.y;
        const int b2 = (i >> 5) & 1, b6 = (i >> 1) & 1;
        float z2 = 1.f - 2.f * (float)b2, z6 = 1.f - 2.f * (float)b6;
        e2 += pr * z2;
        e5 += pr * z6;
        e8 += pr * z2 * z6;
        if (!b2) {
            c32 p = S[wv][swz(i | 32)];
            float cr = a.x * p.x + a.y * p.y;   // Re(conj(a)*p)
            float ci = a.x * p.y - a.y * p.x;   // Im(conj(a)*p)
            e0 += 2.f * cr;
            e1 += 2.f * ci;
            c32 d = S[wv][swz(i ^ 34)];         // flip bits 5 and 1
            float dr = a.x * d.x + a.y * d.y;
            e6 += 2.f * dr;
            e7 += (2.f * (float)b6 - 1.f) * 2.f * dr;
        }
        if (!b6) {
            c32 p = S[wv][swz(i | 2)];
            float cr = a.x * p.x + a.y * p.y;
            float ci = a.x * p.y - a.y * p.x;
            e3 += 2.f * cr;
            e4 += 2.f * ci;
        }
    }
    float e[9] = {e0, e1, e2, e3, e4, e5, e6, e7, e8};
#pragma unroll
    for (int m = 0; m < 9; ++m) {
        float s = e[m];
#pragma unroll
        for (int o = 32; o; o >>= 1) s += __shfl_xor(s, o, 64);
        e[m] = s;
    }
    if (lane == 0) {
#pragma unroll
        for (int m = 0; m < 9; ++m) out[b * 9 + m] = e[m];
    }
}

extern "C" void kernel_launch(void* const* d_in, const int* in_sizes, int n_in,
                              void* d_out, int out_size, void* d_ws, size_t ws_size,
                              hipStream_t stream) {
    const float* x = (const float*)d_in[0];
    const float* w = (const float*)d_in[1];
    float* out = (float*)d_out;
    c32* mats = (c32*)d_ws;

    hipLaunchKernelGGL(build_gates_kernel, dim3(1), dim3(64), 0, stream, w, mats);

    const int batch = in_sizes[0] / 256;   // 8192
    const int nblocks = batch / 4;         // 4 waves (states) per block
    hipLaunchKernelGGL(sim_kernel, dim3(nblocks), dim3(256), 0, stream, x, mats, out);
}

// Round 4
// 32.738 us; speedup vs baseline: 3.9731x; 1.8465x over previous
//
#include <hip/hip_runtime.h>

typedef float2 c32;

__device__ __forceinline__ c32 cmul(c32 a, c32 b) {
    return make_float2(a.x * b.x - a.y * b.y, a.x * b.y + a.y * b.x);
}
__device__ __forceinline__ c32 cmad(c32 a, c32 b, c32 acc) {
    acc.x = fmaf(a.x, b.x, fmaf(-a.y, b.y, acc.x));
    acc.y = fmaf(a.x, b.y, fmaf(a.y, b.x, acc.y));
    return acc;
}

// ---------------- gate-matrix precompute: 20 threads, one column each ------

__device__ __forceinline__ void mk_u3(float th, float ph, float la, c32 U[2][2]) {
    float ct = cosf(0.5f * th), st = sinf(0.5f * th);
    U[0][0] = make_float2(ct, 0.f);
    U[0][1] = make_float2(-cosf(la) * st, -sinf(la) * st);
    U[1][0] = make_float2(cosf(ph) * st, sinf(ph) * st);
    U[1][1] = make_float2(cosf(ph + la) * ct, sinf(ph + la) * ct);
}

__device__ __forceinline__ void lmul_kron(const c32 A[2][2], const c32 B[2][2], c32 m[4]) {
    c32 t[4];
#pragma unroll
    for (int r = 0; r < 4; ++r) {
        c32 acc = make_float2(0.f, 0.f);
#pragma unroll
        for (int k = 0; k < 4; ++k)
            acc = cmad(cmul(A[r >> 1][k >> 1], B[r & 1][k & 1]), m[k], acc);
        t[r] = acc;
    }
#pragma unroll
    for (int r = 0; r < 4; ++r) m[r] = t[r];
}

__global__ void build_gates_kernel(const float* __restrict__ w, c32* __restrict__ mats) {
    const int t = threadIdx.x;
    if (t >= 20) return;
    const int g = t >> 2, c = t & 3;
    const float* p = w + g * 15;
    const int c0 = c >> 1, c1 = c & 1;
    c32 A[2][2], B[2][2], m[4], tmp;

    mk_u3(p[0], p[1], p[2], A);
    mk_u3(p[3], p[4], p[5], B);
#pragma unroll
    for (int r = 0; r < 4; ++r) m[r] = cmul(A[r >> 1][c0], B[r & 1][c1]);
    tmp = m[2]; m[2] = m[3]; m[3] = tmp;                 // CNOT(w0->w1)
    {
        float cc = cosf(0.5f * p[6]), s = sinf(0.5f * p[6]);
        A[0][0] = make_float2(cc, 0.f); A[0][1] = make_float2(-s, 0.f);
        A[1][0] = make_float2(s, 0.f);  A[1][1] = make_float2(cc, 0.f);
        float cz = cosf(0.5f * p[7]), sz = sinf(0.5f * p[7]);
        B[0][0] = make_float2(cz, -sz); B[0][1] = make_float2(0.f, 0.f);
        B[1][0] = make_float2(0.f, 0.f); B[1][1] = make_float2(cz, sz);
        lmul_kron(A, B, m);
    }
    tmp = m[1]; m[1] = m[3]; m[3] = tmp;                 // CNOT(w1->w0)
    {
        float cc = cosf(0.5f * p[8]), s = sinf(0.5f * p[8]);
        A[0][0] = make_float2(cc, 0.f); A[0][1] = make_float2(-s, 0.f);
        A[1][0] = make_float2(s, 0.f);  A[1][1] = make_float2(cc, 0.f);
        B[0][0] = make_float2(1.f, 0.f); B[0][1] = make_float2(0.f, 0.f);
        B[1][0] = make_float2(0.f, 0.f); B[1][1] = make_float2(1.f, 0.f);
        lmul_kron(A, B, m);
    }
    tmp = m[2]; m[2] = m[3]; m[3] = tmp;                 // CNOT(w0->w1)
    mk_u3(p[9], p[10], p[11], A);
    mk_u3(p[12], p[13], p[14], B);
    lmul_kron(A, B, m);
#pragma unroll
    for (int r = 0; r < 4; ++r) mats[g * 16 + r * 4 + c] = m[r];
}

// ---------------- register-window simulator: 4 states per wave ------------
// qubit q <-> bit (7-q).  Lane holds 16 amps (4 window qubits in-register).

#define STRIDE 516   // float2 per state slice (bank-staggered)

__device__ __forceinline__ int swz8(int i) { return i ^ (i >> 4); }
__host__ __device__ constexpr int cswz8(int i) { return i ^ (i >> 4); }

template<int P3, int P2, int P1, int P0>
struct BitMap {
    __device__ static int scatterDyn(int v) {
        return (((v >> 3) & 1) << P3) | (((v >> 2) & 1) << P2) |
               (((v >> 1) & 1) << P1) | ((v & 1) << P0);
    }
    static constexpr int scatter(int v) {
        return (((v >> 3) & 1) << P3) | (((v >> 2) & 1) << P2) |
               (((v >> 1) & 1) << P1) | ((v & 1) << P0);
    }
};

// window maps (reg bit k -> global bit) and lane maps (complement)
using WA = BitMap<7, 6, 5, 4>;  using LA = BitMap<3, 2, 1, 0>;   // q0,q1,q2,q3
using WB = BitMap<3, 2, 1, 0>;  using LB = BitMap<7, 6, 5, 4>;   // q4,q5,q6,q7
using WC = BitMap<7, 4, 3, 0>;  using LC = BitMap<6, 5, 2, 1>;   // q0,q3,q4,q7
using WD = BitMap<7, 5, 3, 1>;  using LD = BitMap<6, 4, 2, 0>;   // q0,q2,q4,q6

// re-layout: write with old map, read with new map (wave-private LDS slice)
template<class WO, class LO, class WN, class LN>
__device__ __forceinline__ void transition(c32* sl, int c, c32 s[16]) {
    const int uo = swz8(LO::scatterDyn(c));
#pragma unroll
    for (int r = 0; r < 16; ++r) sl[uo ^ cswz8(WO::scatter(r))] = s[r];
    const int un = swz8(LN::scatterDyn(c));
#pragma unroll
    for (int r = 0; r < 16; ++r) s[r] = sl[un ^ cswz8(WN::scatter(r))];
}

constexpr int freePos(int A, int B, int k) {
    int cnt = 0;
    for (int p = 0; p < 4; ++p)
        if (p != A && p != B) { if (cnt == k) return p; ++cnt; }
    return -1;
}

// apply 4x4 gate; w0 at reg-bit A, w1 at reg-bit B (row = 2*bitA + bitB)
template<int A, int B>
__device__ __forceinline__ void gate(const c32 m[16], c32 s[16]) {
    constexpr int C0 = freePos(A, B, 0);
    constexpr int C1 = freePos(A, B, 1);
#pragma unroll
    for (int q = 0; q < 4; ++q) {
        const int base = ((q & 1) << C0) | (((q >> 1) & 1) << C1);
        const int i00 = base, i01 = base | (1 << B), i10 = base | (1 << A),
                  i11 = base | (1 << A) | (1 << B);
        c32 a0 = s[i00], a1 = s[i01], a2 = s[i10], a3 = s[i11];
        c32 r0 = cmul(m[0],  a0); r0 = cmad(m[1],  a1, r0); r0 = cmad(m[2],  a2, r0); r0 = cmad(m[3],  a3, r0);
        c32 r1 = cmul(m[4],  a0); r1 = cmad(m[5],  a1, r1); r1 = cmad(m[6],  a2, r1); r1 = cmad(m[7],  a3, r1);
        c32 r2 = cmul(m[8],  a0); r2 = cmad(m[9],  a1, r2); r2 = cmad(m[10], a2, r2); r2 = cmad(m[11], a3, r2);
        c32 r3 = cmul(m[12], a0); r3 = cmad(m[13], a1, r3); r3 = cmad(m[14], a2, r3); r3 = cmad(m[15], a3, r3);
        s[i00] = r0; s[i01] = r1; s[i10] = r2; s[i11] = r3;
    }
}

__device__ __forceinline__ void loadm(const c32* __restrict__ g, int idx, c32 m[16]) {
#pragma unroll
    for (int k = 0; k < 16; ++k) m[k] = g[idx * 16 + k];
}

__global__ __launch_bounds__(64) void sim_kernel(const float* __restrict__ x,
                                                 const c32* __restrict__ gmats,
                                                 float* __restrict__ out) {
    __shared__ c32 TR[4 * STRIDE];
    const int lane = threadIdx.x;      // one wave per block
    const int st   = lane >> 4;        // state within wave (0..3)
    const int c    = lane & 15;        // 16 lanes per state
    const int b    = blockIdx.x * 4 + st;

    // load in layout A (i = r<<4 | c), normalize
    const float* xb = x + (size_t)b * 256 + c;
    c32 s[16];
    float ss = 0.f;
#pragma unroll
    for (int r = 0; r < 16; ++r) {
        float v = xb[r << 4];
        s[r] = make_float2(v, 0.f);
        ss = fmaf(v, v, ss);
    }
#pragma unroll
    for (int o = 8; o; o >>= 1) ss += __shfl_xor(ss, o, 64);
    const float inv = 1.0f / sqrtf(ss);
#pragma unroll
    for (int r = 0; r < 16; ++r) s[r].x *= inv;

    c32* sl = TR + st * STRIDE;
    c32 m[16];

    // P1 (A, m0): (0,1) (2,3) (1,2)
    loadm(gmats, 0, m);
    gate<3, 2>(m, s); gate<1, 0>(m, s); gate<2, 1>(m, s);
    transition<WA, LA, WB, LB>(sl, c, s);
    // P2 (B, m0): (4,5) (6,7) (5,6)
    gate<3, 2>(m, s); gate<1, 0>(m, s); gate<2, 1>(m, s);
    transition<WB, LB, WC, LC>(sl, c, s);
    // P3 (C, m0): (3,4) (7,0)
    gate<2, 1>(m, s); gate<0, 3>(m, s);
    transition<WC, LC, WA, LA>(sl, c, s);
    // P4 (A, m1)
    loadm(gmats, 1, m);
    gate<3, 2>(m, s); gate<1, 0>(m, s); gate<2, 1>(m, s);
    transition<WA, LA, WB, LB>(sl, c, s);
    // P5 (B, m1)
    gate<3, 2>(m, s); gate<1, 0>(m, s); gate<2, 1>(m, s);
    transition<WB, LB, WC, LC>(sl, c, s);
    // P6 (C, m1)
    gate<2, 1>(m, s); gate<0, 3>(m, s);
    transition<WC, LC, WD, LD>(sl, c, s);
    // P7 (D): m2: (2,4)(6,0)(0,2)(4,6); m3: same; m4: (2,6)
    loadm(gmats, 2, m);
    gate<2, 1>(m, s); gate<0, 3>(m, s); gate<3, 2>(m, s); gate<1, 0>(m, s);
    loadm(gmats, 3, m);
    gate<2, 1>(m, s); gate<0, 3>(m, s); gate<3, 2>(m, s); gate<1, 0>(m, s);
    loadm(gmats, 4, m);
    gate<2, 0>(m, s);

    // epilogue in window D: qubit2 = reg-bit 2, qubit6 = reg-bit 0
    float e0 = 0, e1 = 0, e2 = 0, e3 = 0, e4 = 0, e5 = 0, e6 = 0, e7 = 0, e8 = 0;
#pragma unroll
    for (int q = 0; q < 4; ++q) {
        const int f = ((q & 1) << 1) | ((q & 2) << 2);   // free bits r1, r3
        c32 a00 = s[f], a01 = s[f | 1], a10 = s[f | 4], a11 = s[f | 5];
        float n00 = a00.x * a00.x + a00.y * a00.y;
        float n01 = a01.x * a01.x + a01.y * a01.y;
        float n10 = a10.x * a10.x + a10.y * a10.y;
        float n11 = a11.x * a11.x + a11.y * a11.y;
        float z2r = a00.x * a10.x + a00.y * a10.y + a01.x * a11.x + a01.y * a11.y;
        float z2i = a00.x * a10.y - a00.y * a10.x + a01.x * a11.y - a01.y * a11.x;
        float z6r = a00.x * a01.x + a00.y * a01.y + a10.x * a11.x + a10.y * a11.y;
        float z6i = a00.x * a01.y - a00.y * a01.x + a10.x * a11.y - a10.y * a11.x;
        float w1r = a00.x * a11.x + a00.y * a11.y;   // Re(conj(a00)*a11)
        float w2r = a01.x * a10.x + a01.y * a10.y;   // Re(conj(a01)*a10)
        e0 += 2.f * z2r;  e1 += 2.f * z2i;  e2 += n00 + n01 - n10 - n11;
        e3 += 2.f * z6r;  e4 += 2.f * z6i;  e5 += n00 - n01 + n10 - n11;
        e6 += 2.f * (w1r + w2r);  e7 += 2.f * (w2r - w1r);
        e8 += n00 - n01 - n10 + n11;
    }
    float e[9] = {e0, e1, e2, e3, e4, e5, e6, e7, e8};
#pragma unroll
    for (int mm = 0; mm < 9; ++mm) {
        float v = e[mm];
#pragma unroll
        for (int o = 8; o; o >>= 1) v += __shfl_xor(v, o, 64);
        e[mm] = v;
    }
    if (c == 0) {
#pragma unroll
        for (int mm = 0; mm < 9; ++mm) out[b * 9 + mm] = e[mm];
    }
}

extern "C" void kernel_launch(void* const* d_in, const int* in_sizes, int n_in,
                              void* d_out, int out_size, void* d_ws, size_t ws_size,
                              hipStream_t stream) {
    const float* x = (const float*)d_in[0];
    const float* w = (const float*)d_in[1];
    float* out = (float*)d_out;
    c32* mats = (c32*)d_ws;

    hipLaunchKernelGGL(build_gates_kernel, dim3(1), dim3(64), 0, stream, w, mats);

    const int batch = in_sizes[0] / 256;   // 8192
    const int nblocks = batch / 4;         // 4 states per wave, 1 wave per block
    hipLaunchKernelGGL(sim_kernel, dim3(nblocks), dim3(64), 0, stream, x, mats, out);
}